// Round 2
// baseline (442.317 us; speedup 1.0000x reference)
//
#include <hip/hip_runtime.h>
#include <hip/hip_bf16.h>

// EdgeBlock: out[e] = relu(concat(edge[e], node[recv[e]], node[send[e]], g) @ W1 + b1) @ W2 + b2
// Round 2: per-wave edge ownership (16 edges x 128 hidden per wave) --
//   4x fewer gathers/converts per wave, all 12 A-gathers issued upfront,
//   wave-local LDS transpose (no __syncthreads), B from L1-resident ws tables.

typedef __bf16 bf16x8 __attribute__((ext_vector_type(8)));
typedef float f32x4 __attribute__((ext_vector_type(4)));

#define BM 64
#define K1 192

// ws layout:
//   [0, 49152)          W1T bf16 [128][192]   (W1T[n][k] = W1[k][n], k<192)
//   [49152, 65536)      W2T bf16 [64][128]    (W2T[n][k] = W2[k][n])
//   [65536, 66048)      g1  f32  [128]        (b1 + global_attr @ W1[192:256])

__global__ void prep_kernel(const float* __restrict__ W1, const float* __restrict__ b1,
                            const float* __restrict__ W2, const float* __restrict__ gattr,
                            __bf16* __restrict__ W1T, __bf16* __restrict__ W2T,
                            float* __restrict__ g1) {
    int tid = blockIdx.x * blockDim.x + threadIdx.x;
    if (tid < 128 * 192) {
        int n = tid / 192, k = tid % 192;
        W1T[n * 192 + k] = (__bf16)W1[k * 128 + n];
    } else if (tid < 128 * 192 + 64 * 128) {
        int t = tid - 128 * 192;
        int n = t / 128, k = t % 128;
        W2T[n * 128 + k] = (__bf16)W2[k * 64 + n];
    } else if (tid < 128 * 192 + 64 * 128 + 128) {
        int n = tid - (128 * 192 + 64 * 128);
        float acc = b1[n];
        for (int j = 0; j < 64; ++j) acc += gattr[j] * W1[(192 + j) * 128 + n];
        g1[n] = acc;
    }
}

__device__ __forceinline__ f32x4 mk4(float v) {
    f32x4 r; r[0] = v; r[1] = v; r[2] = v; r[3] = v; return r;
}

__global__ __launch_bounds__(256) void edge_mlp_kernel(
    const float* __restrict__ edge_feats, const float* __restrict__ node_feats,
    const int* __restrict__ senders, const int* __restrict__ receivers,
    const __bf16* __restrict__ W1T, const __bf16* __restrict__ W2T,
    const float* __restrict__ g1, const float* __restrict__ b2,
    float* __restrict__ out, int E)
{
    // per-wave 16x128 hidden tile, padded 128->136 (read-side 2-way max)
    __shared__ __bf16 h_lds[4][16][136];  // 17408 B

    const int e0   = blockIdx.x * BM;
    const int lane = threadIdx.x & 63;
    const int w    = threadIdx.x >> 6;   // wave 0..3, owns edges e0+w*16 .. +15
    const int c    = lane & 15;          // edge-row within wave tile / n-col
    const int g    = lane >> 4;          // k-group 0..3

    int row = e0 + w * 16 + c;
    if (row > E - 1) row = E - 1;
    const float* pe = edge_feats + (long)row * 64;
    const float* pr = node_feats + (long)receivers[row] * 64;
    const float* ps = node_feats + (long)senders[row] * 64;

    // ---- stage this wave's A rows: 12 independent 16B loads, one drain ----
    f32x4 st[12];
    {
        const float* bases[3] = { pe, pr, ps };
#pragma unroll
        for (int s = 0; s < 3; ++s)
#pragma unroll
            for (int hh = 0; hh < 2; ++hh) {
                const float* p = bases[s] + hh * 32 + g * 8;
                st[(s * 2 + hh) * 2]     = *(const f32x4*)p;
                st[(s * 2 + hh) * 2 + 1] = *(const f32x4*)(p + 4);
            }
    }
    bf16x8 a[6];
#pragma unroll
    for (int ks = 0; ks < 6; ++ks) {
        bf16x8 t;
#pragma unroll
        for (int j = 0; j < 4; ++j) {
            t[j]     = (__bf16)st[2 * ks][j];
            t[4 + j] = (__bf16)st[2 * ks + 1][j];
        }
        a[ks] = t;
    }

    // ---- GEMM1: acc[nt] (16 edges x 16 cols each), nt = 0..7 ----
    f32x4 acc[8];
#pragma unroll
    for (int nt = 0; nt < 8; ++nt) acc[nt] = mk4(g1[nt * 16 + c]);

#pragma unroll
    for (int nt = 0; nt < 8; ++nt)
#pragma unroll
        for (int ks = 0; ks < 6; ++ks) {
            bf16x8 b = *(const bf16x8*)(W1T + (nt * 16 + c) * K1 + ks * 32 + g * 8);
            acc[nt] = __builtin_amdgcn_mfma_f32_16x16x32_bf16(a[ks], b, acc[nt], 0, 0, 0);
        }

    // ---- relu + bf16 -> wave-local LDS transpose (no cross-wave barrier) ----
#pragma unroll
    for (int nt = 0; nt < 8; ++nt)
#pragma unroll
        for (int r = 0; r < 4; ++r) {
            float v = acc[nt][r];
            v = v > 0.f ? v : 0.f;
            h_lds[w][g * 4 + r][nt * 16 + c] = (__bf16)v;
        }
    asm volatile("s_waitcnt lgkmcnt(0)" ::: "memory");

    // ---- GEMM2: out tile 16 edges x 64 cols ----
    f32x4 acc2[4];
#pragma unroll
    for (int nt = 0; nt < 4; ++nt) acc2[nt] = mk4(b2[nt * 16 + c]);

#pragma unroll
    for (int ks = 0; ks < 4; ++ks) {
        bf16x8 a2 = *(const bf16x8*)&h_lds[w][c][ks * 32 + g * 8];
#pragma unroll
        for (int nt = 0; nt < 4; ++nt) {
            bf16x8 b = *(const bf16x8*)(W2T + (nt * 16 + c) * 128 + ks * 32 + g * 8);
            acc2[nt] = __builtin_amdgcn_mfma_f32_16x16x32_bf16(a2, b, acc2[nt], 0, 0, 0);
        }
    }

    const int orow = e0 + w * 16 + g * 4;
#pragma unroll
    for (int nt = 0; nt < 4; ++nt)
#pragma unroll
        for (int r = 0; r < 4; ++r) {
            if (orow + r < E)
                out[(long)(orow + r) * 64 + nt * 16 + c] = acc2[nt][r];
        }
}

extern "C" void kernel_launch(void* const* d_in, const int* in_sizes, int n_in,
                              void* d_out, int out_size, void* d_ws, size_t ws_size,
                              hipStream_t stream) {
    const float* edge_feats = (const float*)d_in[0];
    const float* node_feats = (const float*)d_in[1];
    const float* gattr      = (const float*)d_in[2];
    const int*   senders    = (const int*)d_in[3];
    const int*   receivers  = (const int*)d_in[4];
    const float* W1         = (const float*)d_in[5];
    const float* b1         = (const float*)d_in[6];
    const float* W2         = (const float*)d_in[7];
    const float* b2         = (const float*)d_in[8];
    float* out = (float*)d_out;

    char* ws = (char*)d_ws;
    __bf16* W1T = (__bf16*)ws;
    __bf16* W2T = (__bf16*)(ws + 49152);
    float*  g1  = (float*)(ws + 49152 + 16384);

    int prep_total = 128 * 192 + 64 * 128 + 128;
    int prep_blocks = (prep_total + 255) / 256;
    prep_kernel<<<prep_blocks, 256, 0, stream>>>(W1, b1, W2, gattr, W1T, W2T, g1);

    const int E = in_sizes[3];  // senders count = N_EDGES
    int grid = (E + BM - 1) / BM;
    edge_mlp_kernel<<<grid, 256, 0, stream>>>(edge_feats, node_feats, senders, receivers,
                                              W1T, W2T, g1, b2, out, E);
}